// Round 1
// baseline (393.756 us; speedup 1.0000x reference)
//
#include <hip/hip_runtime.h>

// DeepFM fused ranker, fp32.
// R5: cut Phase B/C LDS broadcast amplification.
//  - Phase B re-tiled to 8 neurons/lane x 2 rows/lane (was 2x8): per k4 a lane
//    issues 2 act ds_read_b128 (was 8) + 8 weight b128 (L2-coalesced, 16-lane
//    same-address) + 32 v_pk_fma. Per-CU LDS instrs in B drop 4x.
//  - Phase C re-tiled to 4 neurons/lane x 2 rows/lane: ds_read count halves.
//  - Act reads: 16 distinct rows/instr at stride 204 floats -> 2-way bank span
//    aliasing only (free per m136). Weight packs reordered to octet/quad-major.

typedef float v2f __attribute__((ext_vector_type(2)));
static __device__ __forceinline__ v2f bc2(float x) { v2f r; r.x = x; r.y = x; return r; }
static __device__ __forceinline__ float relu1(float x) { return fmaxf(x, 0.f); }

#define ROWS_PER_BLOCK 32
#define ROWS_PER_WAVE 8
#define DI_STRIDE 204            // floats; 51 float4
#define H1_STRIDE 132            // floats; 33 float4

// ---- pre-pass: pair-transposed packed weights ----
// W1p[((o*50 + k4)*8 + q)], o=octet(8 neurons) 0..15, q = p*2+s (p=pair 0..3,
//   s=k-subpair 0..1): {W1[j][c], W1[j+1][c], W1[j][c+1], W1[j+1][c+1]},
//   j = o*8 + 2p, c = 4*k4 + 2s.
// W2p[((o*32 + k4)*4 + q)], o=quad(4 neurons) 0..15, q = p*2+s (p 0..1):
//   same with j = o*4 + 2p, row len 128.
__global__ void pack_weights(const float* __restrict__ W1, const float* __restrict__ W2,
                             float4* __restrict__ W1p, float4* __restrict__ W2p) {
    const int idx = blockIdx.x * blockDim.x + threadIdx.x;
    if (idx < 6400) {
        const int q = idx & 7, rest = idx >> 3;
        const int k4 = rest % 50, o = rest / 50;
        const int j = o * 8 + 2 * (q >> 1), c = 4 * k4 + 2 * (q & 1);
        W1p[idx] = make_float4(W1[j * 200 + c],     W1[(j + 1) * 200 + c],
                               W1[j * 200 + c + 1], W1[(j + 1) * 200 + c + 1]);
    }
    if (idx < 2048) {
        const int q = idx & 3, rest = idx >> 2;
        const int k4 = rest & 31, o = rest >> 5;
        const int j = o * 4 + 2 * (q >> 1), c = 4 * k4 + 2 * (q & 1);
        W2p[idx] = make_float4(W2[j * 128 + c],     W2[(j + 1) * 128 + c],
                               W2[j * 128 + c + 1], W2[(j + 1) * 128 + c + 1]);
    }
}

__global__ __launch_bounds__(256) void deepfm_kernel(
    const int* __restrict__ user_id, const int* __restrict__ item_id,
    const int* __restrict__ gender_, const int* __restrict__ age_,
    const int* __restrict__ occ_, const int* __restrict__ genre_ids,
    const float* __restrict__ genre_mask, const float* __restrict__ dense,
    const float* __restrict__ fo_user, const float* __restrict__ fo_item,
    const float* __restrict__ fo_gender, const float* __restrict__ fo_age,
    const float* __restrict__ fo_occ, const float* __restrict__ fo_genre,
    const float* __restrict__ emb_user, const float* __restrict__ emb_item,
    const float* __restrict__ emb_gender, const float* __restrict__ emb_age,
    const float* __restrict__ emb_occ, const float* __restrict__ emb_genre,
    const float* __restrict__ dense_W, const float* __restrict__ dense_b,
    const float4* __restrict__ W1p, const float* __restrict__ b1,
    const float4* __restrict__ W2p, const float* __restrict__ b2,
    const float* __restrict__ Wout, const float* __restrict__ bout,
    float* __restrict__ out, int B)
{
    __shared__ float lds_di[ROWS_PER_BLOCK][DI_STRIDE];   // 26.1 KB; h1[32][132] overlays
    __shared__ float lds_rs[ROWS_PER_BLOCK];
    __shared__ float lds_part[ROWS_PER_BLOCK][4];

    const int tid = threadIdx.x;
    const int wid = tid >> 6;
    const int lane = tid & 63;
    const int blockRow0 = blockIdx.x * ROWS_PER_BLOCK;

    // ---------------- Phase A: gather + FM first/second order (wave owns 8 rows) ----
    {
        const int rowBase = blockRow0 + wid * ROWS_PER_WAVE;
        int uid[ROWS_PER_WAVE], iid[ROWS_PER_WAVE], gg[ROWS_PER_WAVE],
            aa[ROWS_PER_WAVE], oo[ROWS_PER_WAVE];
        #pragma unroll
        for (int r = 0; r < ROWS_PER_WAVE; ++r) {
            int row = rowBase + r; if (row >= B) row = B - 1;
            uid[r] = user_id[row]; iid[r] = item_id[row];
            gg[r] = gender_[row];  aa[r] = age_[row];  oo[r] = occ_[row];
        }

        #pragma unroll
        for (int r = 0; r < ROWS_PER_WAVE; ++r) {
            int row = rowBase + r; if (row >= B) row = B - 1;
            const int ri = wid * ROWS_PER_WAVE + r;

            int gid[6]; float mk[6]; float msum = 0.f;
            #pragma unroll
            for (int t = 0; t < 6; ++t) {
                gid[t] = genre_ids[row * 6 + t];
                mk[t]  = genre_mask[row * 6 + t];
                msum  += mk[t];
            }
            const float inv_den = 1.0f / fmaxf(msum, 1.0f);

            float pe_sum = 0.f, pe_sq = 0.f;
            {
                float v = (lane < 32) ? emb_user[(size_t)uid[r] * 32 + lane]
                                      : emb_item[(size_t)iid[r] * 32 + (lane - 32)];
                lds_di[ri][lane] = v;
                pe_sum += v; pe_sq += v * v;
            }
            {
                float v = (lane < 32) ? emb_gender[gg[r] * 32 + lane]
                                      : emb_age[aa[r] * 32 + (lane - 32)];
                lds_di[ri][64 + lane] = v;
                pe_sum += v; pe_sq += v * v;
            }
            {
                float v;
                if (lane < 32) {
                    v = emb_occ[oo[r] * 32 + lane];
                } else {
                    const int d = lane - 32;
                    float s = 0.f;
                    #pragma unroll
                    for (int t = 0; t < 6; ++t) s += mk[t] * emb_genre[gid[t] * 32 + d];
                    v = s * inv_den;
                }
                lds_di[ri][128 + lane] = v;
                pe_sum += v; pe_sq += v * v;
            }
            if (lane < 8) lds_di[ri][192 + lane] = dense[(size_t)row * 8 + lane];

            float s2 = pe_sum + __shfl_xor(pe_sum, 32);
            float ss = pe_sq  + __shfl_xor(pe_sq, 32);
            float t2 = 0.5f * (s2 * s2 - ss);
            #pragma unroll
            for (int off = 16; off >= 1; off >>= 1) t2 += __shfl_xor(t2, off);

            float fo = fo_user[uid[r]] + fo_item[iid[r]] + fo_gender[gg[r]]
                     + fo_age[aa[r]] + fo_occ[oo[r]];
            float fg = 0.f;
            #pragma unroll
            for (int t = 0; t < 6; ++t) fg += mk[t] * fo_genre[gid[t]];
            fo += fg * inv_den;
            float dd = 0.f;
            #pragma unroll
            for (int j = 0; j < 8; ++j) dd += dense[(size_t)row * 8 + j] * dense_W[j];
            fo += dd + dense_b[0];

            if (lane == 0) lds_rs[ri] = fo + t2;
        }
    }
    __syncthreads();

    // ---------------- Phase B: h1 = relu(deep_in @ W1^T + b1) ----------------------
    // wave owns neurons [32*wid, 32*wid+32) as 4 octets; lane: jpg=lane&3 -> octet
    // (8 neurons, 4 pairs), rh=lane>>2 -> rows {rh, rh+16}. Per k4: 2 act b128
    // (16 distinct rows -> 2-way span alias, free) + 8 weight b128 (16-lane
    // same-address, L2-coalesced) + 32 v_pk_fma.
    const int jpg = lane & 3;
    const int rh  = lane >> 2;

    v2f acc[2][4];
    #pragma unroll
    for (int r = 0; r < 2; ++r)
        #pragma unroll
        for (int p = 0; p < 4; ++p) acc[r][p] = bc2(0.f);

    {
        const float4* __restrict__ W1b = W1p + (wid * 4 + jpg) * 400;
        const float4* __restrict__ dv = reinterpret_cast<const float4*>(&lds_di[0][0]); // stride 51

        for (int k4 = 0; k4 < 50; ++k4) {
            float4 wq[8];
            #pragma unroll
            for (int q = 0; q < 8; ++q) wq[q] = W1b[k4 * 8 + q];
            const float4 a0 = dv[rh * 51 + k4];
            const float4 a1 = dv[(rh + 16) * 51 + k4];
            #pragma unroll
            for (int p = 0; p < 4; ++p) {
                const v2f w0 = { wq[2 * p].x,     wq[2 * p].y };
                const v2f w1 = { wq[2 * p].z,     wq[2 * p].w };
                const v2f w2 = { wq[2 * p + 1].x, wq[2 * p + 1].y };
                const v2f w3 = { wq[2 * p + 1].z, wq[2 * p + 1].w };
                acc[0][p] = __builtin_elementwise_fma(w0, bc2(a0.x), acc[0][p]);
                acc[0][p] = __builtin_elementwise_fma(w1, bc2(a0.y), acc[0][p]);
                acc[0][p] = __builtin_elementwise_fma(w2, bc2(a0.z), acc[0][p]);
                acc[0][p] = __builtin_elementwise_fma(w3, bc2(a0.w), acc[0][p]);
                acc[1][p] = __builtin_elementwise_fma(w0, bc2(a1.x), acc[1][p]);
                acc[1][p] = __builtin_elementwise_fma(w1, bc2(a1.y), acc[1][p]);
                acc[1][p] = __builtin_elementwise_fma(w2, bc2(a1.z), acc[1][p]);
                acc[1][p] = __builtin_elementwise_fma(w3, bc2(a1.w), acc[1][p]);
            }
        }
    }
    __syncthreads();   // all deep_in reads done; overlay h1

    float* __restrict__ h1b = &lds_di[0][0];   // h1[row][j] at row*132 + j
    {
        const int j0 = (wid * 4 + jpg) * 8;
        const float4 b_lo = *reinterpret_cast<const float4*>(b1 + j0);
        const float4 b_hi = *reinterpret_cast<const float4*>(b1 + j0 + 4);
        #pragma unroll
        for (int r = 0; r < 2; ++r) {
            const int row = rh + 16 * r;
            const float4 lo = make_float4(relu1(acc[r][0].x + b_lo.x), relu1(acc[r][0].y + b_lo.y),
                                          relu1(acc[r][1].x + b_lo.z), relu1(acc[r][1].y + b_lo.w));
            const float4 hi = make_float4(relu1(acc[r][2].x + b_hi.x), relu1(acc[r][2].y + b_hi.y),
                                          relu1(acc[r][3].x + b_hi.z), relu1(acc[r][3].y + b_hi.w));
            reinterpret_cast<float4*>(h1b + row * H1_STRIDE + j0)[0] = lo;
            reinterpret_cast<float4*>(h1b + row * H1_STRIDE + j0)[1] = hi;
        }
    }
    __syncthreads();

    // ---------------- Phase C: h2 = relu(h1 @ W2^T + b2) ---------------------------
    // wave owns neurons [16*wid,16*wid+16) as 4 quads; lane: jpg -> quad (2 pairs),
    // rh -> rows {rh, rh+16}. Per k4: 2 act b128 (2-way span alias, free) +
    // 4 weight b128 + 16 v_pk_fma.
    v2f acc2[2][2];
    #pragma unroll
    for (int r = 0; r < 2; ++r)
        #pragma unroll
        for (int p = 0; p < 2; ++p) acc2[r][p] = bc2(0.f);

    {
        const float4* __restrict__ W2b = W2p + (wid * 4 + jpg) * 128;
        const float4* __restrict__ h1v = reinterpret_cast<const float4*>(h1b); // stride 33

        for (int k4 = 0; k4 < 32; ++k4) {
            float4 wq[4];
            #pragma unroll
            for (int q = 0; q < 4; ++q) wq[q] = W2b[k4 * 4 + q];
            const float4 a0 = h1v[rh * 33 + k4];
            const float4 a1 = h1v[(rh + 16) * 33 + k4];
            #pragma unroll
            for (int p = 0; p < 2; ++p) {
                const v2f w0 = { wq[2 * p].x,     wq[2 * p].y };
                const v2f w1 = { wq[2 * p].z,     wq[2 * p].w };
                const v2f w2 = { wq[2 * p + 1].x, wq[2 * p + 1].y };
                const v2f w3 = { wq[2 * p + 1].z, wq[2 * p + 1].w };
                acc2[0][p] = __builtin_elementwise_fma(w0, bc2(a0.x), acc2[0][p]);
                acc2[0][p] = __builtin_elementwise_fma(w1, bc2(a0.y), acc2[0][p]);
                acc2[0][p] = __builtin_elementwise_fma(w2, bc2(a0.z), acc2[0][p]);
                acc2[0][p] = __builtin_elementwise_fma(w3, bc2(a0.w), acc2[0][p]);
                acc2[1][p] = __builtin_elementwise_fma(w0, bc2(a1.x), acc2[1][p]);
                acc2[1][p] = __builtin_elementwise_fma(w1, bc2(a1.y), acc2[1][p]);
                acc2[1][p] = __builtin_elementwise_fma(w2, bc2(a1.z), acc2[1][p]);
                acc2[1][p] = __builtin_elementwise_fma(w3, bc2(a1.w), acc2[1][p]);
            }
        }
    }

    // ---------------- Phase D: Wout dot + combine ----------------------------------
    {
        const int j0 = (wid * 4 + jpg) * 4;
        const float4 bb2 = *reinterpret_cast<const float4*>(b2 + j0);
        const float4 wo  = *reinterpret_cast<const float4*>(Wout + j0);
        #pragma unroll
        for (int r = 0; r < 2; ++r) {
            const float h0 = relu1(acc2[r][0].x + bb2.x);
            const float h1x = relu1(acc2[r][0].y + bb2.y);
            const float h2x = relu1(acc2[r][1].x + bb2.z);
            const float h3x = relu1(acc2[r][1].y + bb2.w);
            float v = wo.x * h0 + wo.y * h1x + wo.z * h2x + wo.w * h3x;
            v += __shfl_xor(v, 1); v += __shfl_xor(v, 2);
            if (jpg == 0) lds_part[rh + 16 * r][wid] = v;
        }
    }
    __syncthreads();

    if (tid < ROWS_PER_BLOCK) {
        const int row = blockRow0 + tid;
        if (row < B) {
            const float deep = lds_part[tid][0] + lds_part[tid][1]
                             + lds_part[tid][2] + lds_part[tid][3] + bout[0];
            out[row] = deep + lds_rs[tid];
        }
    }
}

extern "C" void kernel_launch(void* const* d_in, const int* in_sizes, int n_in,
                              void* d_out, int out_size, void* d_ws, size_t ws_size,
                              hipStream_t stream) {
    const int B = in_sizes[0];

    float4* W1p = reinterpret_cast<float4*>(d_ws);                  // 6400 float4 = 100 KB
    float4* W2p = reinterpret_cast<float4*>((char*)d_ws + 102400);  // 2048 float4 = 32 KB

    pack_weights<<<25, 256, 0, stream>>>(
        (const float*)d_in[22], (const float*)d_in[24], W1p, W2p);

    const int grid = (B + ROWS_PER_BLOCK - 1) / ROWS_PER_BLOCK;  // 512 at B=16384
    deepfm_kernel<<<grid, 256, 0, stream>>>(
        (const int*)d_in[0],  (const int*)d_in[1],  (const int*)d_in[2],
        (const int*)d_in[3],  (const int*)d_in[4],  (const int*)d_in[5],
        (const float*)d_in[6],  (const float*)d_in[7],
        (const float*)d_in[8],  (const float*)d_in[9],  (const float*)d_in[10],
        (const float*)d_in[11], (const float*)d_in[12], (const float*)d_in[13],
        (const float*)d_in[14], (const float*)d_in[15], (const float*)d_in[16],
        (const float*)d_in[17], (const float*)d_in[18], (const float*)d_in[19],
        (const float*)d_in[20], (const float*)d_in[21],
        W1p, (const float*)d_in[23],
        W2p, (const float*)d_in[25],
        (const float*)d_in[26], (const float*)d_in[27],
        (float*)d_out, B);
}

// Round 2
// 310.812 us; speedup vs baseline: 1.2669x; 1.2669x over previous
//
#include <hip/hip_runtime.h>

// DeepFM fused ranker, fp32.
// R6: balanced MLP tile after R5's register blowup (VGPR 256, occupancy 11.8%,
// 42 MB spill/refetch traffic).
//  - Phase B: 4 neurons/lane x 4 rows/lane (jg=lane&7, rg=lane>>3). Per k4:
//    4 act ds_read_b128 (8 distinct rows -> exact 32-bank cover, 0 conflict)
//    + 4 weight b128 (8-lane same-address, L2-resident) + 32 v_pk_fma.
//    FMA:LDS = 8:1 (2x R4), FMA:global = 8:1 (2x R5), ~48 live VGPRs in loop.
//  - Phase C: 4 neurons/lane x 2 rows/lane (R5 mapping — was not the problem).
//  - Phase A/D unchanged from the proven R4 structure.

typedef float v2f __attribute__((ext_vector_type(2)));
static __device__ __forceinline__ v2f bc2(float x) { v2f r; r.x = x; r.y = x; return r; }
static __device__ __forceinline__ float relu1(float x) { return fmaxf(x, 0.f); }

#define ROWS_PER_BLOCK 32
#define ROWS_PER_WAVE 8
#define DI_STRIDE 204            // floats; 51 float4
#define H1_STRIDE 132            // floats; 33 float4

// ---- pre-pass: pair-transposed packed weights, 4-neuron-group major ----
// W1p[(g*50 + k4)*4 + q], g=0..31 (4 neurons each), q = p*2+s (p=pair 0..1,
//   s=k-subpair 0..1): {W1[j][c], W1[j+1][c], W1[j][c+1], W1[j+1][c+1]},
//   j = g*4 + 2p, c = 4*k4 + 2s.
// W2p[(g*32 + k4)*4 + q], g=0..15: same with j = g*4 + 2p, row len 128.
__global__ void pack_weights(const float* __restrict__ W1, const float* __restrict__ W2,
                             float4* __restrict__ W1p, float4* __restrict__ W2p) {
    const int idx = blockIdx.x * blockDim.x + threadIdx.x;
    if (idx < 6400) {
        const int q = idx & 3, t = idx >> 2;
        const int k4 = t % 50, g = t / 50;
        const int j = g * 4 + 2 * (q >> 1), c = 4 * k4 + 2 * (q & 1);
        W1p[idx] = make_float4(W1[j * 200 + c],     W1[(j + 1) * 200 + c],
                               W1[j * 200 + c + 1], W1[(j + 1) * 200 + c + 1]);
    }
    if (idx < 2048) {
        const int q = idx & 3, t = idx >> 2;
        const int k4 = t & 31, g = t >> 5;
        const int j = g * 4 + 2 * (q >> 1), c = 4 * k4 + 2 * (q & 1);
        W2p[idx] = make_float4(W2[j * 128 + c],     W2[(j + 1) * 128 + c],
                               W2[j * 128 + c + 1], W2[(j + 1) * 128 + c + 1]);
    }
}

__global__ __launch_bounds__(256) void deepfm_kernel(
    const int* __restrict__ user_id, const int* __restrict__ item_id,
    const int* __restrict__ gender_, const int* __restrict__ age_,
    const int* __restrict__ occ_, const int* __restrict__ genre_ids,
    const float* __restrict__ genre_mask, const float* __restrict__ dense,
    const float* __restrict__ fo_user, const float* __restrict__ fo_item,
    const float* __restrict__ fo_gender, const float* __restrict__ fo_age,
    const float* __restrict__ fo_occ, const float* __restrict__ fo_genre,
    const float* __restrict__ emb_user, const float* __restrict__ emb_item,
    const float* __restrict__ emb_gender, const float* __restrict__ emb_age,
    const float* __restrict__ emb_occ, const float* __restrict__ emb_genre,
    const float* __restrict__ dense_W, const float* __restrict__ dense_b,
    const float4* __restrict__ W1p, const float* __restrict__ b1,
    const float4* __restrict__ W2p, const float* __restrict__ b2,
    const float* __restrict__ Wout, const float* __restrict__ bout,
    float* __restrict__ out, int B)
{
    __shared__ float lds_di[ROWS_PER_BLOCK][DI_STRIDE];   // 26.1 KB; h1[32][132] overlays
    __shared__ float lds_rs[ROWS_PER_BLOCK];
    __shared__ float lds_part[ROWS_PER_BLOCK][4];

    const int tid = threadIdx.x;
    const int wid = tid >> 6;
    const int lane = tid & 63;
    const int blockRow0 = blockIdx.x * ROWS_PER_BLOCK;

    // ---------------- Phase A: gather + FM first/second order (wave owns 8 rows) ----
    {
        const int rowBase = blockRow0 + wid * ROWS_PER_WAVE;
        int uid[ROWS_PER_WAVE], iid[ROWS_PER_WAVE], gg[ROWS_PER_WAVE],
            aa[ROWS_PER_WAVE], oo[ROWS_PER_WAVE];
        #pragma unroll
        for (int r = 0; r < ROWS_PER_WAVE; ++r) {
            int row = rowBase + r; if (row >= B) row = B - 1;
            uid[r] = user_id[row]; iid[r] = item_id[row];
            gg[r] = gender_[row];  aa[r] = age_[row];  oo[r] = occ_[row];
        }

        #pragma unroll
        for (int r = 0; r < ROWS_PER_WAVE; ++r) {
            int row = rowBase + r; if (row >= B) row = B - 1;
            const int ri = wid * ROWS_PER_WAVE + r;

            int gid[6]; float mk[6]; float msum = 0.f;
            #pragma unroll
            for (int t = 0; t < 6; ++t) {
                gid[t] = genre_ids[row * 6 + t];
                mk[t]  = genre_mask[row * 6 + t];
                msum  += mk[t];
            }
            const float inv_den = 1.0f / fmaxf(msum, 1.0f);

            float pe_sum = 0.f, pe_sq = 0.f;
            {
                float v = (lane < 32) ? emb_user[(size_t)uid[r] * 32 + lane]
                                      : emb_item[(size_t)iid[r] * 32 + (lane - 32)];
                lds_di[ri][lane] = v;
                pe_sum += v; pe_sq += v * v;
            }
            {
                float v = (lane < 32) ? emb_gender[gg[r] * 32 + lane]
                                      : emb_age[aa[r] * 32 + (lane - 32)];
                lds_di[ri][64 + lane] = v;
                pe_sum += v; pe_sq += v * v;
            }
            {
                float v;
                if (lane < 32) {
                    v = emb_occ[oo[r] * 32 + lane];
                } else {
                    const int d = lane - 32;
                    float s = 0.f;
                    #pragma unroll
                    for (int t = 0; t < 6; ++t) s += mk[t] * emb_genre[gid[t] * 32 + d];
                    v = s * inv_den;
                }
                lds_di[ri][128 + lane] = v;
                pe_sum += v; pe_sq += v * v;
            }
            if (lane < 8) lds_di[ri][192 + lane] = dense[(size_t)row * 8 + lane];

            float s2 = pe_sum + __shfl_xor(pe_sum, 32);
            float ss = pe_sq  + __shfl_xor(pe_sq, 32);
            float t2 = 0.5f * (s2 * s2 - ss);
            #pragma unroll
            for (int off = 16; off >= 1; off >>= 1) t2 += __shfl_xor(t2, off);

            float fo = fo_user[uid[r]] + fo_item[iid[r]] + fo_gender[gg[r]]
                     + fo_age[aa[r]] + fo_occ[oo[r]];
            float fg = 0.f;
            #pragma unroll
            for (int t = 0; t < 6; ++t) fg += mk[t] * fo_genre[gid[t]];
            fo += fg * inv_den;
            float dd = 0.f;
            #pragma unroll
            for (int j = 0; j < 8; ++j) dd += dense[(size_t)row * 8 + j] * dense_W[j];
            fo += dd + dense_b[0];

            if (lane == 0) lds_rs[ri] = fo + t2;
        }
    }
    __syncthreads();

    // ---------------- Phase B: h1 = relu(deep_in @ W1^T + b1) ----------------------
    // wave owns neurons [32*wid, 32*wid+32) as 8 groups of 4; lane: jg=lane&7 ->
    // group (2 pairs), rg=lane>>3 -> rows {rg+8r}. Per k4: 4 act b128 (8 distinct
    // rows, exact 32-bank cover) + 4 weight b128 (8-lane same-addr) + 32 v_pk_fma.
    const int jg = lane & 7;
    const int rg = lane >> 3;

    v2f acc[4][2];
    #pragma unroll
    for (int r = 0; r < 4; ++r) { acc[r][0] = bc2(0.f); acc[r][1] = bc2(0.f); }

    {
        const float4* __restrict__ W1b = W1p + (wid * 8 + jg) * 200;
        const float4* __restrict__ dv = reinterpret_cast<const float4*>(&lds_di[0][0]); // stride 51

        for (int k4 = 0; k4 < 50; ++k4) {
            const float4 wa0 = W1b[k4 * 4 + 0];   // pair0 {j0k0,j1k0,j0k1,j1k1}
            const float4 wa1 = W1b[k4 * 4 + 1];   // pair0 {j0k2,j1k2,j0k3,j1k3}
            const float4 wb0 = W1b[k4 * 4 + 2];   // pair1 k0..k1
            const float4 wb1 = W1b[k4 * 4 + 3];   // pair1 k2..k3
            const v2f p00 = { wa0.x, wa0.y }, p01 = { wa0.z, wa0.w };
            const v2f p02 = { wa1.x, wa1.y }, p03 = { wa1.z, wa1.w };
            const v2f p10 = { wb0.x, wb0.y }, p11 = { wb0.z, wb0.w };
            const v2f p12 = { wb1.x, wb1.y }, p13 = { wb1.z, wb1.w };
            #pragma unroll
            for (int r = 0; r < 4; ++r) {
                const float4 a = dv[(rg + 8 * r) * 51 + k4];
                acc[r][0] = __builtin_elementwise_fma(p00, bc2(a.x), acc[r][0]);
                acc[r][0] = __builtin_elementwise_fma(p01, bc2(a.y), acc[r][0]);
                acc[r][0] = __builtin_elementwise_fma(p02, bc2(a.z), acc[r][0]);
                acc[r][0] = __builtin_elementwise_fma(p03, bc2(a.w), acc[r][0]);
                acc[r][1] = __builtin_elementwise_fma(p10, bc2(a.x), acc[r][1]);
                acc[r][1] = __builtin_elementwise_fma(p11, bc2(a.y), acc[r][1]);
                acc[r][1] = __builtin_elementwise_fma(p12, bc2(a.z), acc[r][1]);
                acc[r][1] = __builtin_elementwise_fma(p13, bc2(a.w), acc[r][1]);
            }
        }
    }
    __syncthreads();   // all deep_in reads done; overlay h1

    float* __restrict__ h1b = &lds_di[0][0];   // h1[row][j] at row*132 + j
    {
        const int j0 = (wid * 8 + jg) * 4;
        const float4 bb = *reinterpret_cast<const float4*>(b1 + j0);
        #pragma unroll
        for (int r = 0; r < 4; ++r) {
            const int row = rg + 8 * r;
            const float4 hv = make_float4(relu1(acc[r][0].x + bb.x), relu1(acc[r][0].y + bb.y),
                                          relu1(acc[r][1].x + bb.z), relu1(acc[r][1].y + bb.w));
            *reinterpret_cast<float4*>(h1b + row * H1_STRIDE + j0) = hv;
        }
    }
    __syncthreads();

    // ---------------- Phase C: h2 = relu(h1 @ W2^T + b2) ---------------------------
    // wave owns neurons [16*wid,16*wid+16) as 4 quads; lane: jq=lane&3 -> quad
    // (2 pairs), rq=lane>>2 -> rows {rq, rq+16}. Per k4: 2 act b128 (2-way alias,
    // free) + 4 weight b128 + 16 v_pk_fma.
    const int jq = lane & 3;
    const int rq = lane >> 2;

    v2f acc2[2][2];
    #pragma unroll
    for (int r = 0; r < 2; ++r) { acc2[r][0] = bc2(0.f); acc2[r][1] = bc2(0.f); }

    {
        const float4* __restrict__ W2b = W2p + (wid * 4 + jq) * 128;
        const float4* __restrict__ h1v = reinterpret_cast<const float4*>(h1b); // stride 33

        for (int k4 = 0; k4 < 32; ++k4) {
            const float4 wa0 = W2b[k4 * 4 + 0];
            const float4 wa1 = W2b[k4 * 4 + 1];
            const float4 wb0 = W2b[k4 * 4 + 2];
            const float4 wb1 = W2b[k4 * 4 + 3];
            const v2f p00 = { wa0.x, wa0.y }, p01 = { wa0.z, wa0.w };
            const v2f p02 = { wa1.x, wa1.y }, p03 = { wa1.z, wa1.w };
            const v2f p10 = { wb0.x, wb0.y }, p11 = { wb0.z, wb0.w };
            const v2f p12 = { wb1.x, wb1.y }, p13 = { wb1.z, wb1.w };
            #pragma unroll
            for (int r = 0; r < 2; ++r) {
                const float4 a = h1v[(rq + 16 * r) * 33 + k4];
                acc2[r][0] = __builtin_elementwise_fma(p00, bc2(a.x), acc2[r][0]);
                acc2[r][0] = __builtin_elementwise_fma(p01, bc2(a.y), acc2[r][0]);
                acc2[r][0] = __builtin_elementwise_fma(p02, bc2(a.z), acc2[r][0]);
                acc2[r][0] = __builtin_elementwise_fma(p03, bc2(a.w), acc2[r][0]);
                acc2[r][1] = __builtin_elementwise_fma(p10, bc2(a.x), acc2[r][1]);
                acc2[r][1] = __builtin_elementwise_fma(p11, bc2(a.y), acc2[r][1]);
                acc2[r][1] = __builtin_elementwise_fma(p12, bc2(a.z), acc2[r][1]);
                acc2[r][1] = __builtin_elementwise_fma(p13, bc2(a.w), acc2[r][1]);
            }
        }
    }

    // ---------------- Phase D: Wout dot + combine ----------------------------------
    {
        const int j0 = (wid * 4 + jq) * 4;
        const float4 bb2 = *reinterpret_cast<const float4*>(b2 + j0);
        const float4 wo  = *reinterpret_cast<const float4*>(Wout + j0);
        #pragma unroll
        for (int r = 0; r < 2; ++r) {
            const float h0 = relu1(acc2[r][0].x + bb2.x);
            const float h1x = relu1(acc2[r][0].y + bb2.y);
            const float h2x = relu1(acc2[r][1].x + bb2.z);
            const float h3x = relu1(acc2[r][1].y + bb2.w);
            float v = wo.x * h0 + wo.y * h1x + wo.z * h2x + wo.w * h3x;
            v += __shfl_xor(v, 1); v += __shfl_xor(v, 2);
            if (jq == 0) lds_part[rq + 16 * r][wid] = v;
        }
    }
    __syncthreads();

    if (tid < ROWS_PER_BLOCK) {
        const int row = blockRow0 + tid;
        if (row < B) {
            const float deep = lds_part[tid][0] + lds_part[tid][1]
                             + lds_part[tid][2] + lds_part[tid][3] + bout[0];
            out[row] = deep + lds_rs[tid];
        }
    }
}

extern "C" void kernel_launch(void* const* d_in, const int* in_sizes, int n_in,
                              void* d_out, int out_size, void* d_ws, size_t ws_size,
                              hipStream_t stream) {
    const int B = in_sizes[0];

    float4* W1p = reinterpret_cast<float4*>(d_ws);                  // 6400 float4 = 100 KB
    float4* W2p = reinterpret_cast<float4*>((char*)d_ws + 102400);  // 2048 float4 = 32 KB

    pack_weights<<<25, 256, 0, stream>>>(
        (const float*)d_in[22], (const float*)d_in[24], W1p, W2p);

    const int grid = (B + ROWS_PER_BLOCK - 1) / ROWS_PER_BLOCK;  // 512 at B=16384
    deepfm_kernel<<<grid, 256, 0, stream>>>(
        (const int*)d_in[0],  (const int*)d_in[1],  (const int*)d_in[2],
        (const int*)d_in[3],  (const int*)d_in[4],  (const int*)d_in[5],
        (const float*)d_in[6],  (const float*)d_in[7],
        (const float*)d_in[8],  (const float*)d_in[9],  (const float*)d_in[10],
        (const float*)d_in[11], (const float*)d_in[12], (const float*)d_in[13],
        (const float*)d_in[14], (const float*)d_in[15], (const float*)d_in[16],
        (const float*)d_in[17], (const float*)d_in[18], (const float*)d_in[19],
        (const float*)d_in[20], (const float*)d_in[21],
        W1p, (const float*)d_in[23],
        W2p, (const float*)d_in[25],
        (const float*)d_in[26], (const float*)d_in[27],
        (float*)d_out, B);
}